// Round 1
// baseline (807.780 us; speedup 1.0000x reference)
//
#include <hip/hip_runtime.h>

#define NPTS 1048576

__device__ __forceinline__ float4 lerp4(const float4 a, const float4 b, const float t) {
    return make_float4(a.x + (b.x - a.x) * t,
                       a.y + (b.y - a.y) * t,
                       a.z + (b.z - a.z) * t,
                       a.w + (b.w - a.w) * t);
}

// Compute clamped coordinate, smoothstep weight, and the two corner indices.
template<int D>
__device__ __forceinline__ void coords(float g, float& t, int& i0, int& i1) {
    float x = (g + 1.0f) * (0.5f * (float)(D - 1));
    x = fminf(fmaxf(x, 0.0f), (float)(D - 1));
    float x0f = floorf(x);
    t = x - x0f;
    t = t * t * (3.0f - 2.0f * t);   // smoothstep
    i0 = (int)x0f;
    i1 = min(i0 + 1, D - 1);
}

// Sample from channel-interleaved [D,H,W,C=4] layout: one float4 per corner.
template<int D>
__device__ __forceinline__ float4 sample_inter(const float4* __restrict__ v,
                                               float gx, float gy, float gz) {
    float tx, ty, tz; int x0, x1, y0, y1, z0, z1;
    coords<D>(gx, tx, x0, x1);
    coords<D>(gy, ty, y0, y1);
    coords<D>(gz, tz, z0, z1);
    const int b00 = (z0 * D + y0) * D;
    const int b01 = (z0 * D + y1) * D;
    const int b10 = (z1 * D + y0) * D;
    const int b11 = (z1 * D + y1) * D;
    float4 c000 = v[b00 + x0], c001 = v[b00 + x1];
    float4 c010 = v[b01 + x0], c011 = v[b01 + x1];
    float4 c100 = v[b10 + x0], c101 = v[b10 + x1];
    float4 c110 = v[b11 + x0], c111 = v[b11 + x1];
    float4 c00 = lerp4(c000, c001, tx);
    float4 c01 = lerp4(c010, c011, tx);
    float4 c10 = lerp4(c100, c101, tx);
    float4 c11 = lerp4(c110, c111, tx);
    float4 c0 = lerp4(c00, c01, ty);
    float4 c1 = lerp4(c10, c11, ty);
    return lerp4(c0, c1, tz);
}

// Sample from native [C=4,D,H,W] layout: per-channel scalar gathers.
template<int D>
__device__ __forceinline__ float4 sample_direct(const float* __restrict__ v,
                                                float gx, float gy, float gz) {
    float tx, ty, tz; int x0, x1, y0, y1, z0, z1;
    coords<D>(gx, tx, x0, x1);
    coords<D>(gy, ty, y0, y1);
    coords<D>(gz, tz, z0, z1);
    const int b00 = (z0 * D + y0) * D;
    const int b01 = (z0 * D + y1) * D;
    const int b10 = (z1 * D + y0) * D;
    const int b11 = (z1 * D + y1) * D;
    float r[4];
#pragma unroll
    for (int c = 0; c < 4; ++c) {
        const float* __restrict__ vc = v + (size_t)c * (D * D * D);
        float c000 = vc[b00 + x0], c001 = vc[b00 + x1];
        float c010 = vc[b01 + x0], c011 = vc[b01 + x1];
        float c100 = vc[b10 + x0], c101 = vc[b10 + x1];
        float c110 = vc[b11 + x0], c111 = vc[b11 + x1];
        float c00 = c000 + (c001 - c000) * tx;
        float c01 = c010 + (c011 - c010) * tx;
        float c10 = c100 + (c101 - c100) * tx;
        float c11 = c110 + (c111 - c110) * tx;
        float c0 = c00 + (c01 - c00) * ty;
        float c1 = c10 + (c11 - c10) * ty;
        r[c] = c0 + (c1 - c0) * tz;
    }
    return make_float4(r[0], r[1], r[2], r[3]);
}

// [C,DHW] -> [DHW,C] channel interleave.
template<int DHW>
__global__ __launch_bounds__(256) void xpose_kernel(const float* __restrict__ in,
                                                    float4* __restrict__ out) {
    int v = blockIdx.x * blockDim.x + threadIdx.x;
    if (v < DHW)
        out[v] = make_float4(in[v], in[v + DHW], in[v + 2 * DHW], in[v + 3 * DHW]);
}

// Main gather: vol0-2 interleaved in ws, vol3 native.
__global__ __launch_bounds__(256) void mg_inter_kernel(
    const float* __restrict__ grid,
    const float4* __restrict__ w0, const float4* __restrict__ w1,
    const float4* __restrict__ w2, const float* __restrict__ v3,
    float* __restrict__ out)
{
    int p = blockIdx.x * blockDim.x + threadIdx.x;   // NPTS % 256 == 0, no guard
    float gx = grid[3 * p + 0];
    float gy = grid[3 * p + 1];
    float gz = grid[3 * p + 2];
    float4 f0 = sample_inter<32>(w0, gx, gy, gz);
    float4 f1 = sample_inter<64>(w1, gx, gy, gz);
    float4 f2 = sample_inter<128>(w2, gx, gy, gz);
    float4 f3 = sample_direct<256>(v3, gx, gy, gz);
    out[ 0 * NPTS + p] = f0.x; out[ 1 * NPTS + p] = f0.y;
    out[ 2 * NPTS + p] = f0.z; out[ 3 * NPTS + p] = f0.w;
    out[ 4 * NPTS + p] = f1.x; out[ 5 * NPTS + p] = f1.y;
    out[ 6 * NPTS + p] = f1.z; out[ 7 * NPTS + p] = f1.w;
    out[ 8 * NPTS + p] = f2.x; out[ 9 * NPTS + p] = f2.y;
    out[10 * NPTS + p] = f2.z; out[11 * NPTS + p] = f2.w;
    out[12 * NPTS + p] = f3.x; out[13 * NPTS + p] = f3.y;
    out[14 * NPTS + p] = f3.z; out[15 * NPTS + p] = f3.w;
}

// Fallback: everything from native layout (no workspace needed).
__global__ __launch_bounds__(256) void mg_direct_kernel(
    const float* __restrict__ grid,
    const float* __restrict__ v0, const float* __restrict__ v1,
    const float* __restrict__ v2, const float* __restrict__ v3,
    float* __restrict__ out)
{
    int p = blockIdx.x * blockDim.x + threadIdx.x;
    float gx = grid[3 * p + 0];
    float gy = grid[3 * p + 1];
    float gz = grid[3 * p + 2];
    float4 f0 = sample_direct<32>(v0, gx, gy, gz);
    float4 f1 = sample_direct<64>(v1, gx, gy, gz);
    float4 f2 = sample_direct<128>(v2, gx, gy, gz);
    float4 f3 = sample_direct<256>(v3, gx, gy, gz);
    out[ 0 * NPTS + p] = f0.x; out[ 1 * NPTS + p] = f0.y;
    out[ 2 * NPTS + p] = f0.z; out[ 3 * NPTS + p] = f0.w;
    out[ 4 * NPTS + p] = f1.x; out[ 5 * NPTS + p] = f1.y;
    out[ 6 * NPTS + p] = f1.z; out[ 7 * NPTS + p] = f1.w;
    out[ 8 * NPTS + p] = f2.x; out[ 9 * NPTS + p] = f2.y;
    out[10 * NPTS + p] = f2.z; out[11 * NPTS + p] = f2.w;
    out[12 * NPTS + p] = f3.x; out[13 * NPTS + p] = f3.y;
    out[14 * NPTS + p] = f3.z; out[15 * NPTS + p] = f3.w;
}

extern "C" void kernel_launch(void* const* d_in, const int* in_sizes, int n_in,
                              void* d_out, int out_size, void* d_ws, size_t ws_size,
                              hipStream_t stream) {
    const float* grid = (const float*)d_in[0];
    const float* v0   = (const float*)d_in[1];   // [4,32,32,32]
    const float* v1   = (const float*)d_in[2];   // [4,64,64,64]
    const float* v2   = (const float*)d_in[3];   // [4,128,128,128]
    const float* v3   = (const float*)d_in[4];   // [4,256,256,256]
    float* out = (float*)d_out;

    constexpr int DHW0 = 32 * 32 * 32;       // 32768
    constexpr int DHW1 = 64 * 64 * 64;       // 262144
    constexpr int DHW2 = 128 * 128 * 128;    // 2097152
    constexpr size_t WS_NEED = (size_t)(DHW0 + DHW1 + DHW2) * 16;

    const int threads = 256;
    const int pt_blocks = NPTS / threads;    // 4096

    if (ws_size >= WS_NEED) {
        float4* w0 = (float4*)d_ws;
        float4* w1 = w0 + DHW0;
        float4* w2 = w1 + DHW1;
        xpose_kernel<DHW0><<<DHW0 / threads, threads, 0, stream>>>(v0, w0);
        xpose_kernel<DHW1><<<DHW1 / threads, threads, 0, stream>>>(v1, w1);
        xpose_kernel<DHW2><<<DHW2 / threads, threads, 0, stream>>>(v2, w2);
        mg_inter_kernel<<<pt_blocks, threads, 0, stream>>>(grid, w0, w1, w2, v3, out);
    } else {
        mg_direct_kernel<<<pt_blocks, threads, 0, stream>>>(grid, v0, v1, v2, v3, out);
    }
}

// Round 2
// 705.619 us; speedup vs baseline: 1.1448x; 1.1448x over previous
//
#include <hip/hip_runtime.h>

#define NPTS 1048576
#define NB 32
#define NBINS (NB * NB * NB)   // 32768

// ---------------- math helpers ----------------

__device__ __forceinline__ float4 lerp4(const float4 a, const float4 b, const float t) {
    return make_float4(a.x + (b.x - a.x) * t,
                       a.y + (b.y - a.y) * t,
                       a.z + (b.z - a.z) * t,
                       a.w + (b.w - a.w) * t);
}

template<int D>
__device__ __forceinline__ void coords(float g, float& t, int& i0, int& i1) {
    float x = (g + 1.0f) * (0.5f * (float)(D - 1));
    x = fminf(fmaxf(x, 0.0f), (float)(D - 1));
    float x0f = floorf(x);
    t = x - x0f;
    t = t * t * (3.0f - 2.0f * t);   // smoothstep
    i0 = (int)x0f;
    i1 = min(i0 + 1, D - 1);
}

template<int D>
__device__ __forceinline__ float4 sample_inter(const float4* __restrict__ v,
                                               float gx, float gy, float gz) {
    float tx, ty, tz; int x0, x1, y0, y1, z0, z1;
    coords<D>(gx, tx, x0, x1);
    coords<D>(gy, ty, y0, y1);
    coords<D>(gz, tz, z0, z1);
    const int b00 = (z0 * D + y0) * D;
    const int b01 = (z0 * D + y1) * D;
    const int b10 = (z1 * D + y0) * D;
    const int b11 = (z1 * D + y1) * D;
    float4 c000 = v[b00 + x0], c001 = v[b00 + x1];
    float4 c010 = v[b01 + x0], c011 = v[b01 + x1];
    float4 c100 = v[b10 + x0], c101 = v[b10 + x1];
    float4 c110 = v[b11 + x0], c111 = v[b11 + x1];
    float4 c00 = lerp4(c000, c001, tx);
    float4 c01 = lerp4(c010, c011, tx);
    float4 c10 = lerp4(c100, c101, tx);
    float4 c11 = lerp4(c110, c111, tx);
    float4 c0 = lerp4(c00, c01, ty);
    float4 c1 = lerp4(c10, c11, ty);
    return lerp4(c0, c1, tz);
}

template<int D>
__device__ __forceinline__ float4 sample_direct(const float* __restrict__ v,
                                                float gx, float gy, float gz) {
    float tx, ty, tz; int x0, x1, y0, y1, z0, z1;
    coords<D>(gx, tx, x0, x1);
    coords<D>(gy, ty, y0, y1);
    coords<D>(gz, tz, z0, z1);
    const int b00 = (z0 * D + y0) * D;
    const int b01 = (z0 * D + y1) * D;
    const int b10 = (z1 * D + y0) * D;
    const int b11 = (z1 * D + y1) * D;
    float r[4];
#pragma unroll
    for (int c = 0; c < 4; ++c) {
        const float* __restrict__ vc = v + (size_t)c * (D * D * D);
        float c000 = vc[b00 + x0], c001 = vc[b00 + x1];
        float c010 = vc[b01 + x0], c011 = vc[b01 + x1];
        float c100 = vc[b10 + x0], c101 = vc[b10 + x1];
        float c110 = vc[b11 + x0], c111 = vc[b11 + x1];
        float c00 = c000 + (c001 - c000) * tx;
        float c01 = c010 + (c011 - c010) * tx;
        float c10 = c100 + (c101 - c100) * tx;
        float c11 = c110 + (c111 - c110) * tx;
        float c0 = c00 + (c01 - c00) * ty;
        float c1 = c10 + (c11 - c10) * ty;
        r[c] = c0 + (c1 - c0) * tz;
    }
    return make_float4(r[0], r[1], r[2], r[3]);
}

// ---------------- transpose [C,DHW] -> [DHW,C] ----------------

template<int DHW>
__global__ __launch_bounds__(256) void xpose_kernel(const float* __restrict__ in,
                                                    float4* __restrict__ out) {
    int v = blockIdx.x * blockDim.x + threadIdx.x;
    if (v < DHW)
        out[v] = make_float4(in[v], in[v + DHW], in[v + 2 * DHW], in[v + 3 * DHW]);
}

// ---------------- counting sort ----------------

__device__ __forceinline__ int bin_of(float gx, float gy, float gz) {
    float ux = fminf(fmaxf((gx + 1.0f) * 0.5f, 0.0f), 1.0f);
    float uy = fminf(fmaxf((gy + 1.0f) * 0.5f, 0.0f), 1.0f);
    float uz = fminf(fmaxf((gz + 1.0f) * 0.5f, 0.0f), 1.0f);
    int bx = min((int)(ux * (float)NB), NB - 1);
    int by = min((int)(uy * (float)NB), NB - 1);
    int bz = min((int)(uz * (float)NB), NB - 1);
    return (bz * NB + by) * NB + bx;
}

__global__ __launch_bounds__(256) void bin_hist_kernel(const float* __restrict__ grid,
                                                       int* __restrict__ bins,
                                                       unsigned* __restrict__ hist) {
    int p = blockIdx.x * blockDim.x + threadIdx.x;
    float gx = grid[3 * p + 0];
    float gy = grid[3 * p + 1];
    float gz = grid[3 * p + 2];
    int b = bin_of(gx, gy, gz);
    bins[p] = b;
    atomicAdd(&hist[b], 1u);
}

// single-workgroup exclusive scan of NBINS=32768 counts (1024 thr x 32 items)
__global__ __launch_bounds__(1024) void scan_kernel(const unsigned* __restrict__ hist,
                                                    unsigned* __restrict__ offsets) {
    __shared__ unsigned partial[1024];
    const int t = threadIdx.x;
    const int base = t * 32;
    unsigned sum = 0;
#pragma unroll
    for (int i = 0; i < 32; ++i) sum += hist[base + i];
    partial[t] = sum;
    __syncthreads();
    // Hillis-Steele inclusive scan over 1024 partials
    for (int off = 1; off < 1024; off <<= 1) {
        unsigned v = (t >= off) ? partial[t - off] : 0u;
        __syncthreads();
        partial[t] += v;
        __syncthreads();
    }
    unsigned run = partial[t] - sum;   // exclusive prefix of this chunk
#pragma unroll
    for (int i = 0; i < 32; ++i) {
        offsets[base + i] = run;
        run += hist[base + i];
    }
}

__global__ __launch_bounds__(256) void scatter_kernel(const float* __restrict__ grid,
                                                      const int* __restrict__ bins,
                                                      unsigned* __restrict__ offsets,
                                                      float4* __restrict__ sorted,
                                                      int* __restrict__ inv) {
    int p = blockIdx.x * blockDim.x + threadIdx.x;
    int b = bins[p];
    unsigned pos = atomicAdd(&offsets[b], 1u);
    float gx = grid[3 * p + 0];
    float gy = grid[3 * p + 1];
    float gz = grid[3 * p + 2];
    sorted[pos] = make_float4(gx, gy, gz, __int_as_float(p));
    inv[p] = (int)pos;
}

// ---------------- main gather over sorted points ----------------

__global__ __launch_bounds__(256) void gather_sorted_kernel(
    const float4* __restrict__ sorted,
    const float4* __restrict__ w0, const float4* __restrict__ w1,
    const float4* __restrict__ w2, const float* __restrict__ v3,
    float4* __restrict__ wsout)   // [NPTS][4] float4 = [NPTS][16] float
{
    // XCD swizzle: give each XCD a contiguous range of sorted points
    int bid = blockIdx.x;                       // 4096 blocks
    int sb = (bid & 7) * (int)(gridDim.x >> 3) + (bid >> 3);
    int s = sb * 256 + (int)threadIdx.x;
    float4 gp = sorted[s];
    float gx = gp.x, gy = gp.y, gz = gp.z;
    float4 f0 = sample_inter<32>(w0, gx, gy, gz);
    float4 f1 = sample_inter<64>(w1, gx, gy, gz);
    float4 f2 = sample_inter<128>(w2, gx, gy, gz);
    float4 f3 = sample_direct<256>(v3, gx, gy, gz);
    float4* w = wsout + (size_t)s * 4;
    w[0] = f0; w[1] = f1; w[2] = f2; w[3] = f3;
}

__global__ __launch_bounds__(256) void permute_kernel(const float4* __restrict__ wsout,
                                                      const int* __restrict__ inv,
                                                      float* __restrict__ out) {
    int p = blockIdx.x * blockDim.x + threadIdx.x;
    int s = inv[p];
    const float4* w = wsout + (size_t)s * 4;
    float4 f0 = w[0], f1 = w[1], f2 = w[2], f3 = w[3];
    out[ 0 * NPTS + p] = f0.x; out[ 1 * NPTS + p] = f0.y;
    out[ 2 * NPTS + p] = f0.z; out[ 3 * NPTS + p] = f0.w;
    out[ 4 * NPTS + p] = f1.x; out[ 5 * NPTS + p] = f1.y;
    out[ 6 * NPTS + p] = f1.z; out[ 7 * NPTS + p] = f1.w;
    out[ 8 * NPTS + p] = f2.x; out[ 9 * NPTS + p] = f2.y;
    out[10 * NPTS + p] = f2.z; out[11 * NPTS + p] = f2.w;
    out[12 * NPTS + p] = f3.x; out[13 * NPTS + p] = f3.y;
    out[14 * NPTS + p] = f3.z; out[15 * NPTS + p] = f3.w;
}

// ---------------- fallback paths (smaller ws) ----------------

__global__ __launch_bounds__(256) void mg_inter_kernel(
    const float* __restrict__ grid,
    const float4* __restrict__ w0, const float4* __restrict__ w1,
    const float4* __restrict__ w2, const float* __restrict__ v3,
    float* __restrict__ out)
{
    int p = blockIdx.x * blockDim.x + threadIdx.x;
    float gx = grid[3 * p + 0];
    float gy = grid[3 * p + 1];
    float gz = grid[3 * p + 2];
    float4 f0 = sample_inter<32>(w0, gx, gy, gz);
    float4 f1 = sample_inter<64>(w1, gx, gy, gz);
    float4 f2 = sample_inter<128>(w2, gx, gy, gz);
    float4 f3 = sample_direct<256>(v3, gx, gy, gz);
    out[ 0 * NPTS + p] = f0.x; out[ 1 * NPTS + p] = f0.y;
    out[ 2 * NPTS + p] = f0.z; out[ 3 * NPTS + p] = f0.w;
    out[ 4 * NPTS + p] = f1.x; out[ 5 * NPTS + p] = f1.y;
    out[ 6 * NPTS + p] = f1.z; out[ 7 * NPTS + p] = f1.w;
    out[ 8 * NPTS + p] = f2.x; out[ 9 * NPTS + p] = f2.y;
    out[10 * NPTS + p] = f2.z; out[11 * NPTS + p] = f2.w;
    out[12 * NPTS + p] = f3.x; out[13 * NPTS + p] = f3.y;
    out[14 * NPTS + p] = f3.z; out[15 * NPTS + p] = f3.w;
}

__global__ __launch_bounds__(256) void mg_direct_kernel(
    const float* __restrict__ grid,
    const float* __restrict__ v0, const float* __restrict__ v1,
    const float* __restrict__ v2, const float* __restrict__ v3,
    float* __restrict__ out)
{
    int p = blockIdx.x * blockDim.x + threadIdx.x;
    float gx = grid[3 * p + 0];
    float gy = grid[3 * p + 1];
    float gz = grid[3 * p + 2];
    float4 f0 = sample_direct<32>(v0, gx, gy, gz);
    float4 f1 = sample_direct<64>(v1, gx, gy, gz);
    float4 f2 = sample_direct<128>(v2, gx, gy, gz);
    float4 f3 = sample_direct<256>(v3, gx, gy, gz);
    out[ 0 * NPTS + p] = f0.x; out[ 1 * NPTS + p] = f0.y;
    out[ 2 * NPTS + p] = f0.z; out[ 3 * NPTS + p] = f0.w;
    out[ 4 * NPTS + p] = f1.x; out[ 5 * NPTS + p] = f1.y;
    out[ 6 * NPTS + p] = f1.z; out[ 7 * NPTS + p] = f1.w;
    out[ 8 * NPTS + p] = f2.x; out[ 9 * NPTS + p] = f2.y;
    out[10 * NPTS + p] = f2.z; out[11 * NPTS + p] = f2.w;
    out[12 * NPTS + p] = f3.x; out[13 * NPTS + p] = f3.y;
    out[14 * NPTS + p] = f3.z; out[15 * NPTS + p] = f3.w;
}

// ---------------- launch ----------------

extern "C" void kernel_launch(void* const* d_in, const int* in_sizes, int n_in,
                              void* d_out, int out_size, void* d_ws, size_t ws_size,
                              hipStream_t stream) {
    const float* grid = (const float*)d_in[0];
    const float* v0   = (const float*)d_in[1];   // [4,32,32,32]
    const float* v1   = (const float*)d_in[2];   // [4,64,64,64]
    const float* v2   = (const float*)d_in[3];   // [4,128,128,128]
    const float* v3   = (const float*)d_in[4];   // [4,256,256,256]
    float* out = (float*)d_out;

    constexpr int DHW0 = 32 * 32 * 32;
    constexpr int DHW1 = 64 * 64 * 64;
    constexpr int DHW2 = 128 * 128 * 128;

    // ws layout (bytes)
    constexpr size_t OFF_WSOUT  = 0;                                   // 64 MB
    constexpr size_t OFF_SORTED = OFF_WSOUT  + (size_t)NPTS * 64;      // 16 MB
    constexpr size_t OFF_W2     = OFF_SORTED + (size_t)NPTS * 16;      // 32 MB
    constexpr size_t OFF_W1     = OFF_W2     + (size_t)DHW2 * 16;      // 4 MB
    constexpr size_t OFF_W0     = OFF_W1     + (size_t)DHW1 * 16;      // 0.5 MB
    constexpr size_t OFF_BINS   = OFF_W0     + (size_t)DHW0 * 16;      // 4 MB
    constexpr size_t OFF_INV    = OFF_BINS   + (size_t)NPTS * 4;       // 4 MB
    constexpr size_t OFF_HIST   = OFF_INV    + (size_t)NPTS * 4;       // 128 KB
    constexpr size_t OFF_OFFS   = OFF_HIST   + (size_t)NBINS * 4;      // 128 KB
    constexpr size_t WS_FULL    = OFF_OFFS   + (size_t)NBINS * 4;      // ~124.8 MB
    constexpr size_t WS_INTER   = (size_t)(DHW0 + DHW1 + DHW2) * 16;   // 36.5 MB

    const int threads = 256;
    const int pt_blocks = NPTS / threads;   // 4096
    char* ws = (char*)d_ws;

    if (ws_size >= WS_FULL) {
        float4*   wsout  = (float4*)(ws + OFF_WSOUT);
        float4*   sorted = (float4*)(ws + OFF_SORTED);
        float4*   w2     = (float4*)(ws + OFF_W2);
        float4*   w1     = (float4*)(ws + OFF_W1);
        float4*   w0     = (float4*)(ws + OFF_W0);
        int*      bins   = (int*)   (ws + OFF_BINS);
        int*      inv    = (int*)   (ws + OFF_INV);
        unsigned* hist   = (unsigned*)(ws + OFF_HIST);
        unsigned* offs   = (unsigned*)(ws + OFF_OFFS);

        hipMemsetAsync(hist, 0, (size_t)NBINS * 4, stream);
        xpose_kernel<DHW0><<<DHW0 / threads, threads, 0, stream>>>(v0, w0);
        xpose_kernel<DHW1><<<DHW1 / threads, threads, 0, stream>>>(v1, w1);
        xpose_kernel<DHW2><<<DHW2 / threads, threads, 0, stream>>>(v2, w2);
        bin_hist_kernel<<<pt_blocks, threads, 0, stream>>>(grid, bins, hist);
        scan_kernel<<<1, 1024, 0, stream>>>(hist, offs);
        scatter_kernel<<<pt_blocks, threads, 0, stream>>>(grid, bins, offs, sorted, inv);
        gather_sorted_kernel<<<pt_blocks, threads, 0, stream>>>(sorted, w0, w1, w2, v3, wsout);
        permute_kernel<<<pt_blocks, threads, 0, stream>>>(wsout, inv, out);
    } else if (ws_size >= WS_INTER) {
        float4* w0 = (float4*)d_ws;
        float4* w1 = w0 + DHW0;
        float4* w2 = w1 + DHW1;
        xpose_kernel<DHW0><<<DHW0 / threads, threads, 0, stream>>>(v0, w0);
        xpose_kernel<DHW1><<<DHW1 / threads, threads, 0, stream>>>(v1, w1);
        xpose_kernel<DHW2><<<DHW2 / threads, threads, 0, stream>>>(v2, w2);
        mg_inter_kernel<<<pt_blocks, threads, 0, stream>>>(grid, w0, w1, w2, v3, out);
    } else {
        mg_direct_kernel<<<pt_blocks, threads, 0, stream>>>(grid, v0, v1, v2, v3, out);
    }
}

// Round 4
// 660.408 us; speedup vs baseline: 1.2232x; 1.0685x over previous
//
#include <hip/hip_runtime.h>

#define NPTS 1048576
#define NB 32
#define NBINS (NB * NB * NB)   // 32768

typedef float v4f __attribute__((ext_vector_type(4)));

__device__ __forceinline__ void nt_store4(const float4& f, float4* p) {
    __builtin_nontemporal_store(*(const v4f*)&f, (v4f*)p);
}

// ---------------- math helpers ----------------

__device__ __forceinline__ float4 lerp4(const float4 a, const float4 b, const float t) {
    return make_float4(a.x + (b.x - a.x) * t,
                       a.y + (b.y - a.y) * t,
                       a.z + (b.z - a.z) * t,
                       a.w + (b.w - a.w) * t);
}

struct CoordW { float tx, ty, tz; int b00, b01, b10, b11, x0, x1; };

template<int D>
__device__ __forceinline__ CoordW mkcoord(float gx, float gy, float gz) {
    CoordW c;
    float x = fminf(fmaxf((gx + 1.0f) * (0.5f * (float)(D - 1)), 0.0f), (float)(D - 1));
    float y = fminf(fmaxf((gy + 1.0f) * (0.5f * (float)(D - 1)), 0.0f), (float)(D - 1));
    float z = fminf(fmaxf((gz + 1.0f) * (0.5f * (float)(D - 1)), 0.0f), (float)(D - 1));
    float xf = floorf(x), yf = floorf(y), zf = floorf(z);
    float tx = x - xf, ty = y - yf, tz = z - zf;
    c.tx = tx * tx * (3.0f - 2.0f * tx);
    c.ty = ty * ty * (3.0f - 2.0f * ty);
    c.tz = tz * tz * (3.0f - 2.0f * tz);
    int x0 = (int)xf, y0 = (int)yf, z0 = (int)zf;
    int y1 = min(y0 + 1, D - 1), z1 = min(z0 + 1, D - 1);
    c.x0 = x0;
    c.x1 = min(x0 + 1, D - 1);
    c.b00 = (z0 * D + y0) * D;
    c.b01 = (z0 * D + y1) * D;
    c.b10 = (z1 * D + y0) * D;
    c.b11 = (z1 * D + y1) * D;
    return c;
}

__device__ __forceinline__ float4 reduce8(const float4* q, const CoordW& c) {
    float4 c00 = lerp4(q[0], q[1], c.tx);
    float4 c01 = lerp4(q[2], q[3], c.tx);
    float4 c10 = lerp4(q[4], q[5], c.tx);
    float4 c11 = lerp4(q[6], q[7], c.tx);
    float4 c0 = lerp4(c00, c01, c.ty);
    float4 c1 = lerp4(c10, c11, c.ty);
    return lerp4(c0, c1, c.tz);
}

// ---------------- fused transpose [C,DHW] -> [DHW,C] for 3 volumes ----------------

#define DHW0 (32 * 32 * 32)
#define DHW1 (64 * 64 * 64)
#define DHW2 (128 * 128 * 128)

__global__ __launch_bounds__(256) void xpose_all_kernel(
    const float* __restrict__ v0, const float* __restrict__ v1, const float* __restrict__ v2,
    float4* __restrict__ w0, float4* __restrict__ w1, float4* __restrict__ w2)
{
    constexpr int B2 = DHW2 / 256, B1 = DHW1 / 256;
    int b = blockIdx.x;
    int t = threadIdx.x;
    if (b < B2) {
        int v = b * 256 + t;
        w2[v] = make_float4(v2[v], v2[v + DHW2], v2[v + 2 * DHW2], v2[v + 3 * DHW2]);
    } else if (b < B2 + B1) {
        int v = (b - B2) * 256 + t;
        w1[v] = make_float4(v1[v], v1[v + DHW1], v1[v + 2 * DHW1], v1[v + 3 * DHW1]);
    } else {
        int v = (b - B2 - B1) * 256 + t;
        w0[v] = make_float4(v0[v], v0[v + DHW0], v0[v + 2 * DHW0], v0[v + 3 * DHW0]);
    }
}

// ---------------- counting sort ----------------

__device__ __forceinline__ int bin_of(float gx, float gy, float gz) {
    float ux = fminf(fmaxf((gx + 1.0f) * 0.5f, 0.0f), 1.0f);
    float uy = fminf(fmaxf((gy + 1.0f) * 0.5f, 0.0f), 1.0f);
    float uz = fminf(fmaxf((gz + 1.0f) * 0.5f, 0.0f), 1.0f);
    int bx = min((int)(ux * (float)NB), NB - 1);
    int by = min((int)(uy * (float)NB), NB - 1);
    int bz = min((int)(uz * (float)NB), NB - 1);
    return (bz * NB + by) * NB + bx;
}

__global__ __launch_bounds__(256) void bin_hist_kernel(const float* __restrict__ grid,
                                                       unsigned* __restrict__ hist) {
    int p = blockIdx.x * blockDim.x + threadIdx.x;
    float gx = grid[3 * p + 0];
    float gy = grid[3 * p + 1];
    float gz = grid[3 * p + 2];
    atomicAdd(&hist[bin_of(gx, gy, gz)], 1u);
}

// single-workgroup exclusive scan of NBINS=32768 counts (1024 thr x 32 items)
__global__ __launch_bounds__(1024) void scan_kernel(const unsigned* __restrict__ hist,
                                                    unsigned* __restrict__ offsets) {
    __shared__ unsigned partial[1024];
    const int t = threadIdx.x;
    const int base = t * 32;
    unsigned sum = 0;
#pragma unroll
    for (int i = 0; i < 32; ++i) sum += hist[base + i];
    partial[t] = sum;
    __syncthreads();
    for (int off = 1; off < 1024; off <<= 1) {
        unsigned v = (t >= off) ? partial[t - off] : 0u;
        __syncthreads();
        partial[t] += v;
        __syncthreads();
    }
    unsigned run = partial[t] - sum;
#pragma unroll
    for (int i = 0; i < 32; ++i) {
        offsets[base + i] = run;
        run += hist[base + i];
    }
}

__global__ __launch_bounds__(256) void scatter_kernel(const float* __restrict__ grid,
                                                      unsigned* __restrict__ offsets,
                                                      float4* __restrict__ sorted,
                                                      int* __restrict__ inv) {
    int p = blockIdx.x * blockDim.x + threadIdx.x;
    float gx = grid[3 * p + 0];
    float gy = grid[3 * p + 1];
    float gz = grid[3 * p + 2];
    int b = bin_of(gx, gy, gz);
    unsigned pos = atomicAdd(&offsets[b], 1u);
    sorted[pos] = make_float4(gx, gy, gz, __int_as_float(p));
    inv[p] = (int)pos;
}

// ---------------- main gather over sorted points (high-MLP version) ----------------

__global__ __launch_bounds__(256, 4) void gather_sorted_kernel(
    const float4* __restrict__ sorted,
    const float4* __restrict__ w0, const float4* __restrict__ w1,
    const float4* __restrict__ w2, const float* __restrict__ v3,
    float4* __restrict__ wsout)
{
    // XCD swizzle: contiguous sorted range per XCD for L2 locality
    int bid = blockIdx.x;
    int sb = (bid & 7) * (int)(gridDim.x >> 3) + (bid >> 3);
    int s = sb * 256 + (int)threadIdx.x;
    float4 gp = sorted[s];
    float gx = gp.x, gy = gp.y, gz = gp.z;

    CoordW c0 = mkcoord<32>(gx, gy, gz);
    CoordW c1 = mkcoord<64>(gx, gy, gz);
    CoordW c2 = mkcoord<128>(gx, gy, gz);
    CoordW c3 = mkcoord<256>(gx, gy, gz);

    // ---- issue ALL loads before any arithmetic (maximize MLP) ----
    float4 qa[8], qb[8], qc[8];
    qa[0] = w0[c0.b00 + c0.x0]; qa[1] = w0[c0.b00 + c0.x1];
    qa[2] = w0[c0.b01 + c0.x0]; qa[3] = w0[c0.b01 + c0.x1];
    qa[4] = w0[c0.b10 + c0.x0]; qa[5] = w0[c0.b10 + c0.x1];
    qa[6] = w0[c0.b11 + c0.x0]; qa[7] = w0[c0.b11 + c0.x1];

    qb[0] = w1[c1.b00 + c1.x0]; qb[1] = w1[c1.b00 + c1.x1];
    qb[2] = w1[c1.b01 + c1.x0]; qb[3] = w1[c1.b01 + c1.x1];
    qb[4] = w1[c1.b10 + c1.x0]; qb[5] = w1[c1.b10 + c1.x1];
    qb[6] = w1[c1.b11 + c1.x0]; qb[7] = w1[c1.b11 + c1.x1];

    qc[0] = w2[c2.b00 + c2.x0]; qc[1] = w2[c2.b00 + c2.x1];
    qc[2] = w2[c2.b01 + c2.x0]; qc[3] = w2[c2.b01 + c2.x1];
    qc[4] = w2[c2.b10 + c2.x0]; qc[5] = w2[c2.b10 + c2.x1];
    qc[6] = w2[c2.b11 + c2.x0]; qc[7] = w2[c2.b11 + c2.x1];

    // vol3: native [C,256^3]; per channel+row load the x-pair as one float2
    // (clamped base + select handles the x0==255 border)
    const int xm = min(c3.x0, 254);
    const bool edge = (c3.x0 == 255);
    float2 qd[16];
#pragma unroll
    for (int ch = 0; ch < 4; ++ch) {
        const float* __restrict__ vc = v3 + (size_t)ch * (256 * 256 * 256);
        qd[ch * 4 + 0] = *(const float2*)(vc + c3.b00 + xm);
        qd[ch * 4 + 1] = *(const float2*)(vc + c3.b01 + xm);
        qd[ch * 4 + 2] = *(const float2*)(vc + c3.b10 + xm);
        qd[ch * 4 + 3] = *(const float2*)(vc + c3.b11 + xm);
    }

    // ---- arithmetic ----
    float4 f0 = reduce8(qa, c0);
    float4 f1 = reduce8(qb, c1);
    float4 f2 = reduce8(qc, c2);

    float r3[4];
#pragma unroll
    for (int ch = 0; ch < 4; ++ch) {
        float v00a = edge ? qd[ch * 4 + 0].y : qd[ch * 4 + 0].x, v00b = qd[ch * 4 + 0].y;
        float v01a = edge ? qd[ch * 4 + 1].y : qd[ch * 4 + 1].x, v01b = qd[ch * 4 + 1].y;
        float v10a = edge ? qd[ch * 4 + 2].y : qd[ch * 4 + 2].x, v10b = qd[ch * 4 + 2].y;
        float v11a = edge ? qd[ch * 4 + 3].y : qd[ch * 4 + 3].x, v11b = qd[ch * 4 + 3].y;
        float c00 = v00a + (v00b - v00a) * c3.tx;
        float c01 = v01a + (v01b - v01a) * c3.tx;
        float c10 = v10a + (v10b - v10a) * c3.tx;
        float c11 = v11a + (v11b - v11a) * c3.tx;
        float e0 = c00 + (c01 - c00) * c3.ty;
        float e1 = c10 + (c11 - c10) * c3.ty;
        r3[ch] = e0 + (e1 - e0) * c3.tz;
    }
    float4 f3 = make_float4(r3[0], r3[1], r3[2], r3[3]);

    float4* w = wsout + (size_t)s * 4;
    nt_store4(f0, w + 0);
    nt_store4(f1, w + 1);
    nt_store4(f2, w + 2);
    nt_store4(f3, w + 3);
}

// ---------------- inverse permute: [sorted][16] -> [16][orig] ----------------

__device__ __forceinline__ void permute_one(const float4* __restrict__ wsout,
                                            const int* __restrict__ inv,
                                            float* __restrict__ out, int p) {
    int s = inv[p];
    const float4* w = wsout + (size_t)s * 4;
    float4 f0 = w[0], f1 = w[1], f2 = w[2], f3 = w[3];
    __builtin_nontemporal_store(f0.x, &out[ 0 * NPTS + p]);
    __builtin_nontemporal_store(f0.y, &out[ 1 * NPTS + p]);
    __builtin_nontemporal_store(f0.z, &out[ 2 * NPTS + p]);
    __builtin_nontemporal_store(f0.w, &out[ 3 * NPTS + p]);
    __builtin_nontemporal_store(f1.x, &out[ 4 * NPTS + p]);
    __builtin_nontemporal_store(f1.y, &out[ 5 * NPTS + p]);
    __builtin_nontemporal_store(f1.z, &out[ 6 * NPTS + p]);
    __builtin_nontemporal_store(f1.w, &out[ 7 * NPTS + p]);
    __builtin_nontemporal_store(f2.x, &out[ 8 * NPTS + p]);
    __builtin_nontemporal_store(f2.y, &out[ 9 * NPTS + p]);
    __builtin_nontemporal_store(f2.z, &out[10 * NPTS + p]);
    __builtin_nontemporal_store(f2.w, &out[11 * NPTS + p]);
    __builtin_nontemporal_store(f3.x, &out[12 * NPTS + p]);
    __builtin_nontemporal_store(f3.y, &out[13 * NPTS + p]);
    __builtin_nontemporal_store(f3.z, &out[14 * NPTS + p]);
    __builtin_nontemporal_store(f3.w, &out[15 * NPTS + p]);
}

__global__ __launch_bounds__(256) void permute_kernel(const float4* __restrict__ wsout,
                                                      const int* __restrict__ inv,
                                                      float* __restrict__ out) {
    int p = blockIdx.x * blockDim.x + threadIdx.x;   // 0 .. NPTS/2-1
    permute_one(wsout, inv, out, p);
    permute_one(wsout, inv, out, p + NPTS / 2);
}

// ---------------- fallback paths ----------------

template<int D>
__device__ __forceinline__ float4 sample_inter(const float4* __restrict__ v,
                                               float gx, float gy, float gz) {
    CoordW c = mkcoord<D>(gx, gy, gz);
    float4 q[8];
    q[0] = v[c.b00 + c.x0]; q[1] = v[c.b00 + c.x1];
    q[2] = v[c.b01 + c.x0]; q[3] = v[c.b01 + c.x1];
    q[4] = v[c.b10 + c.x0]; q[5] = v[c.b10 + c.x1];
    q[6] = v[c.b11 + c.x0]; q[7] = v[c.b11 + c.x1];
    return reduce8(q, c);
}

template<int D>
__device__ __forceinline__ float4 sample_direct(const float* __restrict__ v,
                                                float gx, float gy, float gz) {
    CoordW c = mkcoord<D>(gx, gy, gz);
    float r[4];
#pragma unroll
    for (int ch = 0; ch < 4; ++ch) {
        const float* __restrict__ vc = v + (size_t)ch * (D * D * D);
        float c000 = vc[c.b00 + c.x0], c001 = vc[c.b00 + c.x1];
        float c010 = vc[c.b01 + c.x0], c011 = vc[c.b01 + c.x1];
        float c100 = vc[c.b10 + c.x0], c101 = vc[c.b10 + c.x1];
        float c110 = vc[c.b11 + c.x0], c111 = vc[c.b11 + c.x1];
        float c00 = c000 + (c001 - c000) * c.tx;
        float c01 = c010 + (c011 - c010) * c.tx;
        float c10 = c100 + (c101 - c100) * c.tx;
        float c11 = c110 + (c111 - c110) * c.tx;
        float e0 = c00 + (c01 - c00) * c.ty;
        float e1 = c10 + (c11 - c10) * c.ty;
        r[ch] = e0 + (e1 - e0) * c.tz;
    }
    return make_float4(r[0], r[1], r[2], r[3]);
}

__global__ __launch_bounds__(256) void mg_direct_kernel(
    const float* __restrict__ grid,
    const float* __restrict__ v0, const float* __restrict__ v1,
    const float* __restrict__ v2, const float* __restrict__ v3,
    float* __restrict__ out)
{
    int p = blockIdx.x * blockDim.x + threadIdx.x;
    float gx = grid[3 * p + 0];
    float gy = grid[3 * p + 1];
    float gz = grid[3 * p + 2];
    float4 f0 = sample_direct<32>(v0, gx, gy, gz);
    float4 f1 = sample_direct<64>(v1, gx, gy, gz);
    float4 f2 = sample_direct<128>(v2, gx, gy, gz);
    float4 f3 = sample_direct<256>(v3, gx, gy, gz);
    out[ 0 * NPTS + p] = f0.x; out[ 1 * NPTS + p] = f0.y;
    out[ 2 * NPTS + p] = f0.z; out[ 3 * NPTS + p] = f0.w;
    out[ 4 * NPTS + p] = f1.x; out[ 5 * NPTS + p] = f1.y;
    out[ 6 * NPTS + p] = f1.z; out[ 7 * NPTS + p] = f1.w;
    out[ 8 * NPTS + p] = f2.x; out[ 9 * NPTS + p] = f2.y;
    out[10 * NPTS + p] = f2.z; out[11 * NPTS + p] = f2.w;
    out[12 * NPTS + p] = f3.x; out[13 * NPTS + p] = f3.y;
    out[14 * NPTS + p] = f3.z; out[15 * NPTS + p] = f3.w;
}

__global__ __launch_bounds__(256) void mg_inter_kernel(
    const float* __restrict__ grid,
    const float4* __restrict__ w0, const float4* __restrict__ w1,
    const float4* __restrict__ w2, const float* __restrict__ v3,
    float* __restrict__ out)
{
    int p = blockIdx.x * blockDim.x + threadIdx.x;
    float gx = grid[3 * p + 0];
    float gy = grid[3 * p + 1];
    float gz = grid[3 * p + 2];
    float4 f0 = sample_inter<32>(w0, gx, gy, gz);
    float4 f1 = sample_inter<64>(w1, gx, gy, gz);
    float4 f2 = sample_inter<128>(w2, gx, gy, gz);
    float4 f3 = sample_direct<256>(v3, gx, gy, gz);
    out[ 0 * NPTS + p] = f0.x; out[ 1 * NPTS + p] = f0.y;
    out[ 2 * NPTS + p] = f0.z; out[ 3 * NPTS + p] = f0.w;
    out[ 4 * NPTS + p] = f1.x; out[ 5 * NPTS + p] = f1.y;
    out[ 6 * NPTS + p] = f1.z; out[ 7 * NPTS + p] = f1.w;
    out[ 8 * NPTS + p] = f2.x; out[ 9 * NPTS + p] = f2.y;
    out[10 * NPTS + p] = f2.z; out[11 * NPTS + p] = f2.w;
    out[12 * NPTS + p] = f3.x; out[13 * NPTS + p] = f3.y;
    out[14 * NPTS + p] = f3.z; out[15 * NPTS + p] = f3.w;
}

// ---------------- launch ----------------

extern "C" void kernel_launch(void* const* d_in, const int* in_sizes, int n_in,
                              void* d_out, int out_size, void* d_ws, size_t ws_size,
                              hipStream_t stream) {
    const float* grid = (const float*)d_in[0];
    const float* v0   = (const float*)d_in[1];   // [4,32,32,32]
    const float* v1   = (const float*)d_in[2];   // [4,64,64,64]
    const float* v2   = (const float*)d_in[3];   // [4,128,128,128]
    const float* v3   = (const float*)d_in[4];   // [4,256,256,256]
    float* out = (float*)d_out;

    // ws layout (bytes)
    constexpr size_t OFF_WSOUT  = 0;                                   // 64 MB
    constexpr size_t OFF_SORTED = OFF_WSOUT  + (size_t)NPTS * 64;      // 16 MB
    constexpr size_t OFF_W2     = OFF_SORTED + (size_t)NPTS * 16;      // 32 MB
    constexpr size_t OFF_W1     = OFF_W2     + (size_t)DHW2 * 16;      // 4 MB
    constexpr size_t OFF_W0     = OFF_W1     + (size_t)DHW1 * 16;      // 0.5 MB
    constexpr size_t OFF_INV    = OFF_W0     + (size_t)DHW0 * 16;      // 4 MB
    constexpr size_t OFF_HIST   = OFF_INV    + (size_t)NPTS * 4;       // 128 KB
    constexpr size_t OFF_OFFS   = OFF_HIST   + (size_t)NBINS * 4;      // 128 KB
    constexpr size_t WS_FULL    = OFF_OFFS   + (size_t)NBINS * 4;      // ~120.8 MB
    constexpr size_t WS_INTER   = (size_t)(DHW0 + DHW1 + DHW2) * 16;   // 36.5 MB

    const int threads = 256;
    const int pt_blocks = NPTS / threads;   // 4096
    char* ws = (char*)d_ws;

    if (ws_size >= WS_FULL) {
        float4*   wsout  = (float4*)(ws + OFF_WSOUT);
        float4*   sorted = (float4*)(ws + OFF_SORTED);
        float4*   w2     = (float4*)(ws + OFF_W2);
        float4*   w1     = (float4*)(ws + OFF_W1);
        float4*   w0     = (float4*)(ws + OFF_W0);
        int*      inv    = (int*)   (ws + OFF_INV);
        unsigned* hist   = (unsigned*)(ws + OFF_HIST);
        unsigned* offs   = (unsigned*)(ws + OFF_OFFS);

        (void)hipMemsetAsync(hist, 0, (size_t)NBINS * 4, stream);
        xpose_all_kernel<<<(DHW0 + DHW1 + DHW2) / threads, threads, 0, stream>>>(
            v0, v1, v2, w0, w1, w2);
        bin_hist_kernel<<<pt_blocks, threads, 0, stream>>>(grid, hist);
        scan_kernel<<<1, 1024, 0, stream>>>(hist, offs);
        scatter_kernel<<<pt_blocks, threads, 0, stream>>>(grid, offs, sorted, inv);
        gather_sorted_kernel<<<pt_blocks, threads, 0, stream>>>(sorted, w0, w1, w2, v3, wsout);
        permute_kernel<<<pt_blocks / 2, threads, 0, stream>>>(wsout, inv, out);
    } else if (ws_size >= WS_INTER) {
        float4* w0 = (float4*)d_ws;
        float4* w1 = w0 + DHW0;
        float4* w2 = w1 + DHW1;
        xpose_all_kernel<<<(DHW0 + DHW1 + DHW2) / threads, threads, 0, stream>>>(
            v0, v1, v2, w0, w1, w2);
        mg_inter_kernel<<<pt_blocks, threads, 0, stream>>>(grid, w0, w1, w2, v3, out);
    } else {
        mg_direct_kernel<<<pt_blocks, threads, 0, stream>>>(grid, v0, v1, v2, v3, out);
    }
}